// Round 16
// baseline (534.061 us; speedup 1.0000x reference)
//
#include <hip/hip_runtime.h>
#include <hip/hip_bf16.h>

#define NEG_SLOPE 0.2f
#define IN_DIM 256
#define C1 64
#define C2 32
#define ODIM 40
#define SCAN_CHUNK 4096   // 256 threads * 16 items
#define BSHIFT 12         // bucket = dst >> 12 (4096 nodes/bucket)
#define ECHUNK 8192       // edges per block in bucket passes
#define ECH2 16384        // edges per (bucket,chunk) block in node passes
#define CH 10             // max chunks per bucket

typedef unsigned short ushort16;

__device__ __forceinline__ unsigned bf16_rne(float f) {
    unsigned a = __float_as_uint(f);
    return (a + 0x7FFFu + ((a >> 16) & 1u)) >> 16;   // low 16 bits valid
}
__device__ __forceinline__ void bf16x2_unpack(unsigned u, float& f0, float& f1) {
    f0 = __uint_as_float(u << 16);
    f1 = __uint_as_float(u & 0xFFFF0000u);
}

// ---------------- CSR build: bucket sort, then in-bucket counting sort ----------------

__global__ void k_bhist(const int* __restrict__ dst, int E, int* __restrict__ gh,
                        int nblk, int nb) {
    __shared__ int h[32];
    int t = threadIdx.x;
    if (t < 32) h[t] = 0;
    __syncthreads();
    int base = blockIdx.x * ECHUNK;
    int end = min(base + ECHUNK, E);
    for (int i = base + t; i < end; i += 256) atomicAdd(&h[dst[i] >> BSHIFT], 1);
    __syncthreads();
    if (t < nb) gh[t * nblk + blockIdx.x] = h[t];
}

__global__ void k_bscan(int* __restrict__ gh, int L) {
    __shared__ int lds[256];
    __shared__ int carry;
    int t = threadIdx.x;
    if (t == 0) carry = 0;
    __syncthreads();
    for (int base = 0; base < L; base += 256) {
        int v = (base + t < L) ? gh[base + t] : 0;
        lds[t] = v; __syncthreads();
        for (int off = 1; off < 256; off <<= 1) {
            int u = (t >= off) ? lds[t - off] : 0;
            __syncthreads();
            lds[t] += u;
            __syncthreads();
        }
        if (base + t < L) gh[base + t] = lds[t] - v + carry;
        __syncthreads();
        if (t == 0) carry += lds[255];
        __syncthreads();
    }
}

__global__ void k_bplace(const int* __restrict__ src, const int* __restrict__ dst, int E,
                         const int* __restrict__ gh, int nblk, int nb,
                         int2* __restrict__ pairs) {
    __shared__ int cur[32];
    int t = threadIdx.x;
    if (t < nb) cur[t] = gh[t * nblk + blockIdx.x];
    __syncthreads();
    int base = blockIdx.x * ECHUNK;
    int end = min(base + ECHUNK, E);
    for (int i = base + t; i < end; i += 256) {
        int d = dst[i];
        int pos = atomicAdd(&cur[d >> BSHIFT], 1);
        pairs[pos] = make_int2(src[i], d);
    }
}

__device__ __forceinline__ void bc_map(int blk, int* b, int* c) {
    int xcd = blk & 7, k = blk >> 3;
    *b = (k & 3) * 8 + xcd;
    *c = k >> 2;
}

__global__ __launch_bounds__(512)
void k_nhist(const int2* __restrict__ pairs, const int* __restrict__ gh, int nblk,
             int nb, int E, int* __restrict__ chist) {
    __shared__ int h[4096];
    int b, c; bc_map(blockIdx.x, &b, &c);
    if (b >= nb) return;
    for (int i = threadIdx.x; i < 4096; i += 512) h[i] = 0;
    __syncthreads();
    int estart = gh[b * nblk];
    int eend = (b + 1 < nb) ? gh[(b + 1) * nblk] : E;
    int s0 = estart + c * ECH2;
    int s1 = min(s0 + ECH2, eend);
    for (int i = s0 + threadIdx.x; i < s1; i += 512)
        atomicAdd(&h[pairs[i].y & 4095], 1);
    __syncthreads();
    int* out = chist + ((size_t)b * CH + c) * 4096;
    for (int i = threadIdx.x; i < 4096; i += 512) out[i] = h[i];
}

__global__ void k_cnt(const int* __restrict__ chist, int* __restrict__ cnt, int n) {
    int i = blockIdx.x * 256 + threadIdx.x;
    if (i >= n) return;
    int b = i >> BSHIFT, j = i & 4095;
    const int* p = chist + ((size_t)b * CH) * 4096 + j;
    int s = 1;
#pragma unroll
    for (int c = 0; c < CH; c++) s += p[c * 4096];
    cnt[i] = s;
}

__global__ void k_scan1(const int* __restrict__ cnt, int n, int* __restrict__ bsums) {
    __shared__ int lds[256];
    int t = threadIdx.x;
    int base = blockIdx.x * SCAN_CHUNK + t * 16;
    int s = 0;
#pragma unroll
    for (int i = 0; i < 16; i++) { int idx = base + i; s += (idx < n) ? cnt[idx] : 0; }
    lds[t] = s; __syncthreads();
    for (int off = 128; off > 0; off >>= 1) {
        if (t < off) lds[t] += lds[t + off];
        __syncthreads();
    }
    if (t == 0) bsums[blockIdx.x] = lds[0];
}

__global__ void k_scan2(int* bsums, int nb, int* row_ptr, int n, int total) {
    __shared__ int lds[256];
    int t = threadIdx.x;
    int v = (t < nb) ? bsums[t] : 0;
    lds[t] = v; __syncthreads();
    for (int off = 1; off < 256; off <<= 1) {
        int u = (t >= off) ? lds[t - off] : 0;
        __syncthreads();
        lds[t] += u;
        __syncthreads();
    }
    if (t < nb) bsums[t] = lds[t] - v;
    if (t == 0) row_ptr[n] = total;
}

__global__ void k_scan3(const int* __restrict__ cnt, int n, const int* __restrict__ bsums,
                        int* __restrict__ row_ptr) {
    __shared__ int lds[256];
    int t = threadIdx.x;
    int base = blockIdx.x * SCAN_CHUNK + t * 16;
    int loc[16];
    int s = 0;
#pragma unroll
    for (int i = 0; i < 16; i++) {
        int idx = base + i;
        int c = (idx < n) ? cnt[idx] : 0;
        loc[i] = s; s += c;
    }
    lds[t] = s; __syncthreads();
    for (int off = 1; off < 256; off <<= 1) {
        int u = (t >= off) ? lds[t - off] : 0;
        __syncthreads();
        lds[t] += u;
        __syncthreads();
    }
    int texcl = lds[t] - s + bsums[blockIdx.x];
#pragma unroll
    for (int i = 0; i < 16; i++) {
        int idx = base + i;
        if (idx < n) row_ptr[idx] = texcl + loc[i];
    }
}

__global__ void k_selfloop(const int* __restrict__ row_ptr, int n, int* __restrict__ adj) {
    int i = blockIdx.x * 256 + threadIdx.x;
    if (i < n) adj[row_ptr[i]] = i;
}

__global__ void k_nscan(int* __restrict__ chist, const int* __restrict__ row_ptr, int n) {
    int i = blockIdx.x * 256 + threadIdx.x;
    if (i >= n) return;
    int b = i >> BSHIFT, j = i & 4095;
    int* p = chist + ((size_t)b * CH) * 4096 + j;
    int s = row_ptr[i] + 1;  // slot 0 = self-loop
#pragma unroll
    for (int c = 0; c < CH; c++) { int t = p[c * 4096]; p[c * 4096] = s; s += t; }
}

__global__ __launch_bounds__(512)
void k_place2(const int2* __restrict__ pairs, const int* __restrict__ gh, int nblk,
              int nb, int E, const int* __restrict__ chist, int* __restrict__ adj) {
    __shared__ int cur[4096];
    int b, c; bc_map(blockIdx.x, &b, &c);
    if (b >= nb) return;
    const int* cs = chist + ((size_t)b * CH + c) * 4096;
    for (int i = threadIdx.x; i < 4096; i += 512) cur[i] = cs[i];
    __syncthreads();
    int estart = gh[b * nblk];
    int eend = (b + 1 < nb) ? gh[(b + 1) * nblk] : E;
    int s0 = estart + c * ECH2;
    int s1 = min(s0 + ECH2, eend);
    for (int i = s0 + threadIdx.x; i < s1; i += 512) {
        int2 p = pairs[i];
        int pos = atomicAdd(&cur[p.y & 4095], 1);
        adj[pos] = p.x;
    }
}

// ---------------- GEMM1: h1b(bf16) = x @ W1 ----------------
// 64 rows/block; coalesced LDS staging of x (stride 33, conflict-free); wave = 16-col
// quarter, lane = row; W1/att reads wave-uniform -> SGPR. acc[16], #pragma unroll 1
// on k-loops to cap live ranges (r14 spill fix). Partial alpha per quarter.

__global__ __launch_bounds__(256, 4)
void k_gemm1(const float* __restrict__ x, const float* __restrict__ W1,
             const float* __restrict__ attS, const float* __restrict__ attD,
             ushort16* __restrict__ h1b, float* __restrict__ asP,
             float* __restrict__ adP, int n) {
    __shared__ float xs[64 * 33];    // [r][k], stride 33
    int t = threadIdx.x;
    int q = t >> 6, lane = t & 63;   // q = column quarter, lane = row
    int cq = q * 16;
    int row0 = blockIdx.x * 64;
    int row = row0 + lane;
    bool active = row < n;

    float acc[16];
#pragma unroll
    for (int c = 0; c < 16; c++) acc[c] = 0.f;

#pragma unroll 1
    for (int k0 = 0; k0 < IN_DIM; k0 += 32) {
        if (k0) __syncthreads();
        // stage x[row0..row0+64)[k0..k0+32): 512 float4, 2/thread, coalesced
#pragma unroll
        for (int i = 0; i < 2; i++) {
            int fid = i * 256 + t;          // 0..511
            int r = fid >> 3;               // 0..63
            int kk = (fid & 7) * 4;         // 0..28
            int gr = row0 + r; if (gr >= n) gr = n - 1;
            float4 v = *(const float4*)&x[(size_t)gr * IN_DIM + k0 + kk];
            float* xp = &xs[r * 33 + kk];
            xp[0] = v.x; xp[1] = v.y; xp[2] = v.z; xp[3] = v.w;
        }
        __syncthreads();
        const float* xrow = &xs[lane * 33];
#pragma unroll 1
        for (int kk = 0; kk < 32; kk += 4) {
            float x0 = xrow[kk + 0];
            float x1 = xrow[kk + 1];
            float x2 = xrow[kk + 2];
            float x3 = xrow[kk + 3];
            const float* wb = W1 + (size_t)(k0 + kk) * C1 + cq;  // wave-uniform
#pragma unroll
            for (int c = 0; c < 16; c++) acc[c] = fmaf(x0, wb[c], acc[c]);
#pragma unroll
            for (int c = 0; c < 16; c++) acc[c] = fmaf(x1, wb[C1 + c], acc[c]);
#pragma unroll
            for (int c = 0; c < 16; c++) acc[c] = fmaf(x2, wb[2 * C1 + c], acc[c]);
#pragma unroll
            for (int c = 0; c < 16; c++) acc[c] = fmaf(x3, wb[3 * C1 + c], acc[c]);
        }
    }

    if (!active) return;
    float vs = 0.f, vd = 0.f;
#pragma unroll
    for (int c = 0; c < 16; c++) {
        vs = fmaf(acc[c], attS[cq + c], vs);   // uniform -> SGPR
        vd = fmaf(acc[c], attD[cq + c], vd);
    }
    asP[(size_t)q * n + row] = vs;
    adP[(size_t)q * n + row] = vd;

    uint4* hp = (uint4*)((ushort16*)h1b + (size_t)row * C1 + cq);
    unsigned p0 = bf16_rne(acc[0])  | (bf16_rne(acc[1])  << 16);
    unsigned p1 = bf16_rne(acc[2])  | (bf16_rne(acc[3])  << 16);
    unsigned p2 = bf16_rne(acc[4])  | (bf16_rne(acc[5])  << 16);
    unsigned p3 = bf16_rne(acc[6])  | (bf16_rne(acc[7])  << 16);
    unsigned p4 = bf16_rne(acc[8])  | (bf16_rne(acc[9])  << 16);
    unsigned p5 = bf16_rne(acc[10]) | (bf16_rne(acc[11]) << 16);
    unsigned p6 = bf16_rne(acc[12]) | (bf16_rne(acc[13]) << 16);
    unsigned p7 = bf16_rne(acc[14]) | (bf16_rne(acc[15]) << 16);
    hp[0] = make_uint4(p0, p1, p2, p3);
    hp[1] = make_uint4(p4, p5, p6, p7);
}

// combine per-quarter alpha partials
__global__ void k_alphaC(const float* __restrict__ asP, const float* __restrict__ adP,
                         float* __restrict__ as1, float* __restrict__ ad1, int n) {
    int i = blockIdx.x * 256 + threadIdx.x;
    if (i < n) {
        as1[i] = (asP[i] + asP[(size_t)n + i]) +
                 (asP[2 * (size_t)n + i] + asP[3 * (size_t)n + i]);
        ad1[i] = (adP[i] + adP[(size_t)n + i]) +
                 (adP[2 * (size_t)n + i] + adP[3 * (size_t)n + i]);
    }
}

// ---------------- Layer-1 aggregation (bf16 gather, 128B rows) ----------------
// wave per dst; g=lane>>3 picks 1 of 8 edges, cq=lane&7 picks 16B of row.
// lanes >= deg: w=0, s=d -> inert.

__global__ __launch_bounds__(256)
void k_agg1(const ushort16* __restrict__ h1b, const float* __restrict__ as1,
            const float* __restrict__ ad1, const int* __restrict__ row_ptr,
            const int* __restrict__ adj, const float* __restrict__ b1,
            float* __restrict__ h1out, int n) {
    int wave = (blockIdx.x * 256 + threadIdx.x) >> 6;
    int lane = threadIdx.x & 63;
    if (wave >= n) return;
    int d = wave;
    int beg = row_ptr[d], end = row_ptr[d + 1];
    float adv = ad1[d];
    int g = lane >> 3, cq = lane & 7;
    float acc[8];
#pragma unroll
    for (int k = 0; k < 8; k++) acc[k] = 0.f;
    float dsum = 0.f;

#define AGG1_ROUND(E_) { \
        int se = __shfl(s, (E_)); \
        float we = __shfl(w, (E_)); \
        uint4 u = ((const uint4*)(h1b + (size_t)se * C1))[cq]; \
        float f0, f1; \
        bf16x2_unpack(u.x, f0, f1); acc[0]=fmaf(we,f0,acc[0]); acc[1]=fmaf(we,f1,acc[1]); \
        bf16x2_unpack(u.y, f0, f1); acc[2]=fmaf(we,f0,acc[2]); acc[3]=fmaf(we,f1,acc[3]); \
        bf16x2_unpack(u.z, f0, f1); acc[4]=fmaf(we,f0,acc[4]); acc[5]=fmaf(we,f1,acc[5]); \
        bf16x2_unpack(u.w, f0, f1); acc[6]=fmaf(we,f0,acc[6]); acc[7]=fmaf(we,f1,acc[7]); }

    for (int base = beg; base < end; base += 64) {
        int cnt = min(64, end - base);
        int s = d; float w = 0.f;
        if (lane < cnt) {
            s = adj[base + lane];
            float lg = as1[s] + adv;
            lg = lg > 0.f ? lg : NEG_SLOPE * lg;
            w = expf(lg);
            dsum += w;
        }
        int j = 0;
        for (; j + 32 <= cnt; j += 32) {   // 4 rounds of 8 edges -> 4 loads in flight
            AGG1_ROUND(j + g)
            AGG1_ROUND(j + 8 + g)
            AGG1_ROUND(j + 16 + g)
            AGG1_ROUND(j + 24 + g)
        }
        for (; j < cnt; j += 8) AGG1_ROUND(j + g)
    }
#undef AGG1_ROUND

#pragma unroll
    for (int off = 32; off > 0; off >>= 1) dsum += __shfl_xor(dsum, off);
#pragma unroll
    for (int off = 8; off <= 32; off <<= 1) {
#pragma unroll
        for (int k = 0; k < 8; k++) acc[k] += __shfl_xor(acc[k], off);
    }
    if (g == 0) {
        float inv = 1.f / dsum;
        float4 bv0 = ((const float4*)b1)[cq * 2];
        float4 bv1 = ((const float4*)b1)[cq * 2 + 1];
        float4 o0, o1;
        o0.x = acc[0] * inv + bv0.x; o0.x = o0.x > 0.f ? o0.x : 0.f;
        o0.y = acc[1] * inv + bv0.y; o0.y = o0.y > 0.f ? o0.y : 0.f;
        o0.z = acc[2] * inv + bv0.z; o0.z = o0.z > 0.f ? o0.z : 0.f;
        o0.w = acc[3] * inv + bv0.w; o0.w = o0.w > 0.f ? o0.w : 0.f;
        o1.x = acc[4] * inv + bv1.x; o1.x = o1.x > 0.f ? o1.x : 0.f;
        o1.y = acc[5] * inv + bv1.y; o1.y = o1.y > 0.f ? o1.y : 0.f;
        o1.z = acc[6] * inv + bv1.z; o1.z = o1.z > 0.f ? o1.z : 0.f;
        o1.w = acc[7] * inv + bv1.w; o1.w = o1.w > 0.f ? o1.w : 0.f;
        float4* op = (float4*)(h1out + (size_t)d * C1 + cq * 8);
        op[0] = o0; op[1] = o1;
    }
}

// ---------------- GEMM2 + alpha2: stores bf16 h2b; as2/ad2 from exact fp32 ----------------

__global__ __launch_bounds__(256)
void k_gemm2(const float* __restrict__ h1out, const float* __restrict__ W2,
             const float* __restrict__ attS, const float* __restrict__ attD,
             ushort16* __restrict__ h2b, float* __restrict__ as2,
             float* __restrict__ ad2, int n) {
    __shared__ float w2t[C2 * 68];
    __shared__ float sAttS[C2], sAttD[C2];
    int t = threadIdx.x;
    for (int i = t; i < C1 * C2; i += 256) {
        int k = i >> 5, c = i & 31;
        w2t[c * 68 + k] = W2[i];
    }
    if (t < C2) { sAttS[t] = attS[t]; sAttD[t] = attD[t]; }
    __syncthreads();
    int wave = t >> 6, lane = t & 63;
    int col = lane & 31, half = lane >> 5;
    int rowbase = blockIdx.x * 32 + wave * 8;
    const float* wrow = &w2t[col * 68];
    for (int rr = 0; rr < 8; rr += 2) {
        int row = rowbase + rr + half;
        if (row >= n) return;
        float acc = 0.f;
#pragma unroll
        for (int k = 0; k < C1; k += 4) {
            float4 wv = *(const float4*)&wrow[k];
            float4 xv = *(const float4*)&h1out[(size_t)row * C1 + k];
            acc = fmaf(xv.x, wv.x, acc);
            acc = fmaf(xv.y, wv.y, acc);
            acc = fmaf(xv.z, wv.z, acc);
            acc = fmaf(xv.w, wv.w, acc);
        }
        h2b[(size_t)row * C2 + col] = (ushort16)bf16_rne(acc);
        float vs = acc * sAttS[col], vd = acc * sAttD[col];
#pragma unroll
        for (int off = 16; off > 0; off >>= 1) {
            vs += __shfl_xor(vs, off);
            vd += __shfl_xor(vd, off);
        }
        if (col == 0) { as2[row] = vs; ad2[row] = vd; }
    }
}

// ---------------- Layer-2 aggregation (bf16 gather, 64B rows) -> emb ----------------
// g=lane>>2 picks 1 of 16 edges, cq=lane&3 picks 16B of row.

__global__ __launch_bounds__(256)
void k_agg2(const ushort16* __restrict__ h2b, const float* __restrict__ as2,
            const float* __restrict__ ad2, const int* __restrict__ row_ptr,
            const int* __restrict__ adj, const float* __restrict__ b2,
            float* __restrict__ emb, int n) {
    int wave = (blockIdx.x * 256 + threadIdx.x) >> 6;
    int lane = threadIdx.x & 63;
    if (wave >= n) return;
    int d = wave;
    int beg = row_ptr[d], end = row_ptr[d + 1];
    float adv = ad2[d];
    int g = lane >> 2, cq = lane & 3;
    float acc[8];
#pragma unroll
    for (int k = 0; k < 8; k++) acc[k] = 0.f;
    float dsum = 0.f;

#define AGG2_ROUND(E_) { \
        int se = __shfl(s, (E_)); \
        float we = __shfl(w, (E_)); \
        uint4 u = ((const uint4*)(h2b + (size_t)se * C2))[cq]; \
        float f0, f1; \
        bf16x2_unpack(u.x, f0, f1); acc[0]=fmaf(we,f0,acc[0]); acc[1]=fmaf(we,f1,acc[1]); \
        bf16x2_unpack(u.y, f0, f1); acc[2]=fmaf(we,f0,acc[2]); acc[3]=fmaf(we,f1,acc[3]); \
        bf16x2_unpack(u.z, f0, f1); acc[4]=fmaf(we,f0,acc[4]); acc[5]=fmaf(we,f1,acc[5]); \
        bf16x2_unpack(u.w, f0, f1); acc[6]=fmaf(we,f0,acc[6]); acc[7]=fmaf(we,f1,acc[7]); }

    for (int base = beg; base < end; base += 64) {
        int cnt = min(64, end - base);
        int s = d; float w = 0.f;
        if (lane < cnt) {
            s = adj[base + lane];
            float lg = as2[s] + adv;
            lg = lg > 0.f ? lg : NEG_SLOPE * lg;
            w = expf(lg);
            dsum += w;
        }
        int j = 0;
        for (; j + 64 <= cnt; j += 64) {   // 4 rounds of 16 edges
            AGG2_ROUND(j + g)
            AGG2_ROUND(j + 16 + g)
            AGG2_ROUND(j + 32 + g)
            AGG2_ROUND(j + 48 + g)
        }
        for (; j < cnt; j += 16) AGG2_ROUND(j + g)
    }
#undef AGG2_ROUND

#pragma unroll
    for (int off = 32; off > 0; off >>= 1) dsum += __shfl_xor(dsum, off);
#pragma unroll
    for (int off = 4; off <= 32; off <<= 1) {
#pragma unroll
        for (int k = 0; k < 8; k++) acc[k] += __shfl_xor(acc[k], off);
    }
    if (g == 0) {
        float inv = 1.f / dsum;
        float4 bv0 = ((const float4*)b2)[cq * 2];
        float4 bv1 = ((const float4*)b2)[cq * 2 + 1];
        float4 o0, o1;
        o0.x = acc[0] * inv + bv0.x; o0.x = o0.x > 0.f ? o0.x : 0.f;
        o0.y = acc[1] * inv + bv0.y; o0.y = o0.y > 0.f ? o0.y : 0.f;
        o0.z = acc[2] * inv + bv0.z; o0.z = o0.z > 0.f ? o0.z : 0.f;
        o0.w = acc[3] * inv + bv0.w; o0.w = o0.w > 0.f ? o0.w : 0.f;
        o1.x = acc[4] * inv + bv1.x; o1.x = o1.x > 0.f ? o1.x : 0.f;
        o1.y = acc[5] * inv + bv1.y; o1.y = o1.y > 0.f ? o1.y : 0.f;
        o1.z = acc[6] * inv + bv1.z; o1.z = o1.z > 0.f ? o1.z : 0.f;
        o1.w = acc[7] * inv + bv1.w; o1.w = o1.w > 0.f ? o1.w : 0.f;
        float4* op = (float4*)(emb + (size_t)d * C2 + cq * 8);
        op[0] = o0; op[1] = o1;
    }
}

// ---------------- logits = emb @ fcW + fcb ----------------

__global__ __launch_bounds__(256)
void k_logits(const float* __restrict__ emb, const float* __restrict__ fcW,
              const float* __restrict__ fcb, float* __restrict__ out, int n) {
    __shared__ float w[C2 * ODIM];
    __shared__ float b[ODIM];
    int t = threadIdx.x;
    for (int i = t; i < C2 * ODIM; i += 256) w[i] = fcW[i];
    if (t < ODIM) b[t] = fcb[t];
    __syncthreads();
    int lane = t & 63;
    int row = blockIdx.x * 4 + (t >> 6);
    if (row >= n) return;
    float acc = (lane < ODIM) ? b[lane] : 0.f;
    const float4* er = (const float4*)&emb[(size_t)row * C2];
#pragma unroll
    for (int c4 = 0; c4 < 8; c4++) {
        float4 e = er[c4];
        int c = c4 * 4;
        if (lane < ODIM) {
            acc = fmaf(e.x, w[(c + 0) * ODIM + lane], acc);
            acc = fmaf(e.y, w[(c + 1) * ODIM + lane], acc);
            acc = fmaf(e.z, w[(c + 2) * ODIM + lane], acc);
            acc = fmaf(e.w, w[(c + 3) * ODIM + lane], acc);
        }
    }
    if (lane < ODIM) out[(size_t)row * ODIM + lane] = acc;
}

// ---------------- launch ----------------

extern "C" void kernel_launch(void* const* d_in, const int* in_sizes, int n_in,
                              void* d_out, int out_size, void* d_ws, size_t ws_size,
                              hipStream_t stream) {
    const float* x    = (const float*)d_in[0];
    const int*   ei   = (const int*)d_in[1];
    const float* W1   = (const float*)d_in[2];
    const float* aS1  = (const float*)d_in[3];
    const float* aD1  = (const float*)d_in[4];
    const float* b1   = (const float*)d_in[5];
    const float* W2   = (const float*)d_in[6];
    const float* aS2  = (const float*)d_in[7];
    const float* aD2  = (const float*)d_in[8];
    const float* b2   = (const float*)d_in[9];
    const float* fcW  = (const float*)d_in[10];
    const float* fcb  = (const float*)d_in[11];

    const int N = in_sizes[0] / IN_DIM;
    const int E = in_sizes[1] / 2;
    const int* src = ei;
    const int* dst = ei + E;

    // workspace layout
    ushort16* h1b = (ushort16*)d_ws;                 // N*64 ushorts (12.8MB); pre-gemm1: chist
    float* h1out  = (float*)((char*)d_ws + (size_t)N * C1 * 2);  // N*64 floats (pre-agg1: pairs)
    float* as1    = h1out + (size_t)N * C1;          // N
    float* ad1    = as1 + N;
    float* as2    = ad1 + N;
    float* ad2    = as2 + N;
    float* asP    = ad2 + N;                         // 4N (per-quarter partials)
    float* adP    = asP + 4 * (size_t)N;             // 4N
    int*   cnt    = (int*)(adP + 4 * (size_t)N);     // N
    int*   row_ptr = cnt + N;                        // N+1
    int*   bsums   = row_ptr + (N + 1);              // <=256
    int*   adj     = bsums + 256;                    // E+N
    int*   gh      = adj + (E + N);                  // nb*nblkE (~10K)

    int2* pairs = (int2*)h1out;                      // E int2; dead after k_place2
    int*  chist = (int*)h1b;                         // nb*CH*4096 ints; dead before gemm1
    ushort16* h2b = (ushort16*)h1b;                  // N*32 ushorts; h1b dead after agg1

    float* emb    = (float*)d_out;                   // N*32
    float* logits = emb + (size_t)N * C2;            // N*40

    int nbN   = (N + 255) / 256;
    int nbS   = (N + SCAN_CHUNK - 1) / SCAN_CHUNK;   // 25
    int nblkE = (E + ECHUNK - 1) / ECHUNK;           // ~391
    int nb    = (N + (1 << BSHIFT) - 1) >> BSHIFT;   // ~25 buckets (<= 32)
    int nBC   = 8 * 4 * CH;

    // CSR build — no per-edge global atomics
    k_bhist<<<nblkE, 256, 0, stream>>>(dst, E, gh, nblkE, nb);
    k_bscan<<<1, 256, 0, stream>>>(gh, nb * nblkE);
    k_bplace<<<nblkE, 256, 0, stream>>>(src, dst, E, gh, nblkE, nb, pairs);
    k_nhist<<<nBC, 512, 0, stream>>>(pairs, gh, nblkE, nb, E, chist);
    k_cnt<<<nbN, 256, 0, stream>>>(chist, cnt, N);
    k_scan1<<<nbS, 256, 0, stream>>>(cnt, N, bsums);
    k_scan2<<<1, 256, 0, stream>>>(bsums, nbS, row_ptr, N, E + N);
    k_scan3<<<nbS, 256, 0, stream>>>(cnt, N, bsums, row_ptr);
    k_selfloop<<<nbN, 256, 0, stream>>>(row_ptr, N, adj);
    k_nscan<<<nbN, 256, 0, stream>>>(chist, row_ptr, N);
    k_place2<<<nBC, 512, 0, stream>>>(pairs, gh, nblkE, nb, E, chist, adj);

    // GAT layers
    int nbG1 = (N + 63) / 64;
    k_gemm1<<<nbG1, 256, 0, stream>>>(x, W1, aS1, aD1, h1b, asP, adP, N);
    k_alphaC<<<nbN, 256, 0, stream>>>(asP, adP, as1, ad1, N);
    int nbA = (N + 3) / 4;
    k_agg1<<<nbA, 256, 0, stream>>>(h1b, as1, ad1, row_ptr, adj, b1, h1out, N);
    int nbG2 = (N + 31) / 32;
    k_gemm2<<<nbG2, 256, 0, stream>>>(h1out, W2, aS2, aD2, h2b, as2, ad2, N);
    k_agg2<<<nbA, 256, 0, stream>>>(h2b, as2, ad2, row_ptr, adj, b2, emb, N);
    k_logits<<<nbA, 256, 0, stream>>>(emb, fcW, fcb, logits, N);
}

// Round 17
// 421.778 us; speedup vs baseline: 1.2662x; 1.2662x over previous
//
#include <hip/hip_runtime.h>
#include <hip/hip_bf16.h>

#define NEG_SLOPE 0.2f
#define IN_DIM 256
#define C1 64
#define C2 32
#define ODIM 40
#define SCAN_CHUNK 4096   // 256 threads * 16 items
#define BSHIFT 12         // bucket = dst >> 12 (4096 nodes/bucket)
#define ECHUNK 8192       // edges per block in bucket passes
#define ECH2 16384        // edges per (bucket,chunk) block in node passes
#define CH 10             // max chunks per bucket
#define SRCMASK 0x1FFFF   // 17 bits: src < 131072

typedef unsigned short ushort16;

__device__ __forceinline__ unsigned bf16_rne(float f) {
    unsigned a = __float_as_uint(f);
    return (a + 0x7FFFu + ((a >> 16) & 1u)) >> 16;   // low 16 bits valid
}
__device__ __forceinline__ void bf16x2_unpack(unsigned u, float& f0, float& f1) {
    f0 = __uint_as_float(u << 16);
    f1 = __uint_as_float(u & 0xFFFF0000u);
}

// ---------------- CSR build: bucket sort (packed uints), then in-bucket counting sort ----

__global__ void k_bhist(const int* __restrict__ dst, int E, int* __restrict__ gh,
                        int nblk, int nb) {
    __shared__ int h[32];
    int t = threadIdx.x;
    if (t < 32) h[t] = 0;
    __syncthreads();
    int base = blockIdx.x * ECHUNK;
    int end = min(base + ECHUNK, E);
    for (int i = base + t; i < end; i += 256) atomicAdd(&h[dst[i] >> BSHIFT], 1);
    __syncthreads();
    if (t < nb) gh[t * nblk + blockIdx.x] = h[t];
}

__global__ void k_bscan(int* __restrict__ gh, int L) {
    __shared__ int lds[256];
    __shared__ int carry;
    int t = threadIdx.x;
    if (t == 0) carry = 0;
    __syncthreads();
    for (int base = 0; base < L; base += 256) {
        int v = (base + t < L) ? gh[base + t] : 0;
        lds[t] = v; __syncthreads();
        for (int off = 1; off < 256; off <<= 1) {
            int u = (t >= off) ? lds[t - off] : 0;
            __syncthreads();
            lds[t] += u;
            __syncthreads();
        }
        if (base + t < L) gh[base + t] = lds[t] - v + carry;
        __syncthreads();
        if (t == 0) carry += lds[255];
        __syncthreads();
    }
}

// bucket-partition edges into packed uints; block-local LDS sort so global
// writes are 25 contiguous coalesced runs (no random 8B scatter).
__global__ __launch_bounds__(256)
void k_bplace(const int* __restrict__ src, const int* __restrict__ dst, int E,
              const int* __restrict__ gh, int nblk, int nb,
              unsigned* __restrict__ pairs) {
    __shared__ int cnt32[32], lofs[33], lcur[32], delta[32];
    __shared__ unsigned buf[ECHUNK];   // 32 KB
    int t = threadIdx.x;
    if (t < 32) cnt32[t] = 0;
    __syncthreads();
    int base = blockIdx.x * ECHUNK;
    int end = min(base + ECHUNK, E);
    for (int i = base + t; i < end; i += 256) atomicAdd(&cnt32[dst[i] >> BSHIFT], 1);
    __syncthreads();
    if (t == 0) {
        int s = 0;
        for (int b = 0; b < 32; b++) { lofs[b] = s; s += cnt32[b]; }
        lofs[32] = s;
    }
    __syncthreads();
    if (t < 32) {
        lcur[t] = lofs[t];
        delta[t] = (t < nb) ? (gh[t * nblk + blockIdx.x] - lofs[t]) : 0;
    }
    __syncthreads();
    for (int i = base + t; i < end; i += 256) {
        int d = dst[i];
        int b = d >> BSHIFT;
        int p = atomicAdd(&lcur[b], 1);
        buf[p] = (unsigned)src[i] | ((unsigned)(d & 4095) << 17);
    }
    __syncthreads();
    int m = end - base;
    for (int j = t; j < m; j += 256) {
        // binary search: bucket b with lofs[b] <= j < lofs[b+1]
        int lo = 0, hi = 31;
        while (lo < hi) { int mid = (lo + hi + 1) >> 1; if (lofs[mid] <= j) lo = mid; else hi = mid - 1; }
        pairs[j + delta[lo]] = buf[j];
    }
}

__device__ __forceinline__ void bc_map(int blk, int* b, int* c) {
    int xcd = blk & 7, k = blk >> 3;
    *b = (k & 3) * 8 + xcd;
    *c = k >> 2;
}

__global__ __launch_bounds__(512)
void k_nhist(const unsigned* __restrict__ pairs, const int* __restrict__ gh, int nblk,
             int nb, int E, int* __restrict__ chist) {
    __shared__ int h[4096];
    int b, c; bc_map(blockIdx.x, &b, &c);
    if (b >= nb) return;
    for (int i = threadIdx.x; i < 4096; i += 512) h[i] = 0;
    __syncthreads();
    int estart = gh[b * nblk];
    int eend = (b + 1 < nb) ? gh[(b + 1) * nblk] : E;
    int s0 = estart + c * ECH2;
    int s1 = min(s0 + ECH2, eend);
    for (int i = s0 + threadIdx.x; i < s1; i += 512)
        atomicAdd(&h[(pairs[i] >> 17) & 4095], 1);
    __syncthreads();
    int* out = chist + ((size_t)b * CH + c) * 4096;
    for (int i = threadIdx.x; i < 4096; i += 512) out[i] = h[i];
}

__global__ void k_cnt(const int* __restrict__ chist, int* __restrict__ cnt, int n) {
    int i = blockIdx.x * 256 + threadIdx.x;
    if (i >= n) return;
    int b = i >> BSHIFT, j = i & 4095;
    const int* p = chist + ((size_t)b * CH) * 4096 + j;
    int s = 1;
#pragma unroll
    for (int c = 0; c < CH; c++) s += p[c * 4096];
    cnt[i] = s;
}

__global__ void k_scan1(const int* __restrict__ cnt, int n, int* __restrict__ bsums) {
    __shared__ int lds[256];
    int t = threadIdx.x;
    int base = blockIdx.x * SCAN_CHUNK + t * 16;
    int s = 0;
#pragma unroll
    for (int i = 0; i < 16; i++) { int idx = base + i; s += (idx < n) ? cnt[idx] : 0; }
    lds[t] = s; __syncthreads();
    for (int off = 128; off > 0; off >>= 1) {
        if (t < off) lds[t] += lds[t + off];
        __syncthreads();
    }
    if (t == 0) bsums[blockIdx.x] = lds[0];
}

__global__ void k_scan2(int* bsums, int nb, int* row_ptr, int n, int total) {
    __shared__ int lds[256];
    int t = threadIdx.x;
    int v = (t < nb) ? bsums[t] : 0;
    lds[t] = v; __syncthreads();
    for (int off = 1; off < 256; off <<= 1) {
        int u = (t >= off) ? lds[t - off] : 0;
        __syncthreads();
        lds[t] += u;
        __syncthreads();
    }
    if (t < nb) bsums[t] = lds[t] - v;
    if (t == 0) row_ptr[n] = total;
}

__global__ void k_scan3(const int* __restrict__ cnt, int n, const int* __restrict__ bsums,
                        int* __restrict__ row_ptr) {
    __shared__ int lds[256];
    int t = threadIdx.x;
    int base = blockIdx.x * SCAN_CHUNK + t * 16;
    int loc[16];
    int s = 0;
#pragma unroll
    for (int i = 0; i < 16; i++) {
        int idx = base + i;
        int c = (idx < n) ? cnt[idx] : 0;
        loc[i] = s; s += c;
    }
    lds[t] = s; __syncthreads();
    for (int off = 1; off < 256; off <<= 1) {
        int u = (t >= off) ? lds[t - off] : 0;
        __syncthreads();
        lds[t] += u;
        __syncthreads();
    }
    int texcl = lds[t] - s + bsums[blockIdx.x];
#pragma unroll
    for (int i = 0; i < 16; i++) {
        int idx = base + i;
        if (idx < n) row_ptr[idx] = texcl + loc[i];
    }
}

__global__ void k_selfloop(const int* __restrict__ row_ptr, int n, int* __restrict__ adj) {
    int i = blockIdx.x * 256 + threadIdx.x;
    if (i < n) adj[row_ptr[i]] = i;
}

__global__ void k_nscan(int* __restrict__ chist, const int* __restrict__ row_ptr, int n) {
    int i = blockIdx.x * 256 + threadIdx.x;
    if (i >= n) return;
    int b = i >> BSHIFT, j = i & 4095;
    int* p = chist + ((size_t)b * CH) * 4096 + j;
    int s = row_ptr[i] + 1;  // slot 0 = self-loop
#pragma unroll
    for (int c = 0; c < CH; c++) { int t = p[c * 4096]; p[c * 4096] = s; s += t; }
}

__global__ __launch_bounds__(512)
void k_place2(const unsigned* __restrict__ pairs, const int* __restrict__ gh, int nblk,
              int nb, int E, const int* __restrict__ chist, int* __restrict__ adj,
              int bbase) {
    __shared__ int cur[4096];
    int b, c; bc_map(blockIdx.x, &b, &c);
    if (b >= nb) return;
    const int* cs = chist + ((size_t)b * CH + c) * 4096;
    for (int i = threadIdx.x; i < 4096; i += 512) cur[i] = cs[i];
    __syncthreads();
    int estart = gh[b * nblk];
    int eend = (b + 1 < nb) ? gh[(b + 1) * nblk] : E;
    int s0 = estart + c * ECH2;
    int s1 = min(s0 + ECH2, eend);
    int nbase = b << BSHIFT; (void)nbase; (void)bbase;
    for (int i = s0 + threadIdx.x; i < s1; i += 512) {
        unsigned p = pairs[i];
        int pos = atomicAdd(&cur[(p >> 17) & 4095], 1);
        adj[pos] = (int)(p & SRCMASK);
    }
}

// ---------------- GEMM1: h1b(bf16) = x @ W1; partial alpha from exact fp32 acc ----------------
// Two column-half blocks per 256 rows; lane = row; W1/att reads wave-uniform -> SGPR.
// [r12/r15-measured: 123us, VGPR 32, no spill — do not restructure]

__global__ __launch_bounds__(256, 4)
void k_gemm1(const float* __restrict__ x, const float* __restrict__ W1,
             const float* __restrict__ attS, const float* __restrict__ attD,
             ushort16* __restrict__ h1b, float* __restrict__ asP,
             float* __restrict__ adP, int n) {
    int t = threadIdx.x;
    int wave = t >> 6, lane = t & 63;
    int half = blockIdx.x & 1;
    int chalf = half * 32;                              // block-uniform column half
    int row = (blockIdx.x >> 1) * 256 + wave * 64 + lane;
    bool active = row < n;
    int rowc = active ? row : n - 1;
    const float4* xr = (const float4*)(x + (size_t)rowc * IN_DIM);

    float acc[32];
#pragma unroll
    for (int c = 0; c < 32; c++) acc[c] = 0.f;

#define FMA_K(XC, KK) { \
        const float* wk = wb + (KK) * C1; \
        _Pragma("unroll") \
        for (int c = 0; c < 32; c++) acc[c] = fmaf((XC), wk[c], acc[c]); }

    for (int k0 = 0; k0 < 16; k0++) {                   // BK = 16
        float4 xv0 = xr[k0 * 4 + 0];
        float4 xv1 = xr[k0 * 4 + 1];
        float4 xv2 = xr[k0 * 4 + 2];
        float4 xv3 = xr[k0 * 4 + 3];
        const float* wb = W1 + (size_t)(k0 * 16) * C1 + chalf;  // uniform
        FMA_K(xv0.x, 0)  FMA_K(xv0.y, 1)  FMA_K(xv0.z, 2)  FMA_K(xv0.w, 3)
        FMA_K(xv1.x, 4)  FMA_K(xv1.y, 5)  FMA_K(xv1.z, 6)  FMA_K(xv1.w, 7)
        FMA_K(xv2.x, 8)  FMA_K(xv2.y, 9)  FMA_K(xv2.z, 10) FMA_K(xv2.w, 11)
        FMA_K(xv3.x, 12) FMA_K(xv3.y, 13) FMA_K(xv3.z, 14) FMA_K(xv3.w, 15)
    }
#undef FMA_K

    if (!active) return;
    float vs = 0.f, vd = 0.f;
#pragma unroll
    for (int c = 0; c < 32; c++) {
        vs = fmaf(acc[c], attS[chalf + c], vs);   // uniform -> SGPR
        vd = fmaf(acc[c], attD[chalf + c], vd);
    }
    asP[half * n + row] = vs;
    adP[half * n + row] = vd;

    uint4* hp = (uint4*)((ushort16*)h1b + (size_t)row * C1 + chalf);
#pragma unroll
    for (int j = 0; j < 4; j++) {
        unsigned p0 = bf16_rne(acc[j*8+0]) | (bf16_rne(acc[j*8+1]) << 16);
        unsigned p1 = bf16_rne(acc[j*8+2]) | (bf16_rne(acc[j*8+3]) << 16);
        unsigned p2 = bf16_rne(acc[j*8+4]) | (bf16_rne(acc[j*8+5]) << 16);
        unsigned p3 = bf16_rne(acc[j*8+6]) | (bf16_rne(acc[j*8+7]) << 16);
        hp[j] = make_uint4(p0, p1, p2, p3);
    }
}

// combine per-half alpha partials
__global__ void k_alphaC(const float* __restrict__ asP, const float* __restrict__ adP,
                         float* __restrict__ as1, float* __restrict__ ad1, int n) {
    int i = blockIdx.x * 256 + threadIdx.x;
    if (i < n) {
        as1[i] = asP[i] + asP[(size_t)n + i];
        ad1[i] = adP[i] + adP[(size_t)n + i];
    }
}

// ---------------- Layer-1 aggregation (bf16 gather, 128B rows) ----------------

__global__ __launch_bounds__(256)
void k_agg1(const ushort16* __restrict__ h1b, const float* __restrict__ as1,
            const float* __restrict__ ad1, const int* __restrict__ row_ptr,
            const int* __restrict__ adj, const float* __restrict__ b1,
            float* __restrict__ h1out, int n) {
    int wave = (blockIdx.x * 256 + threadIdx.x) >> 6;
    int lane = threadIdx.x & 63;
    if (wave >= n) return;
    int d = wave;
    int beg = row_ptr[d], end = row_ptr[d + 1];
    float adv = ad1[d];
    int g = lane >> 3, cq = lane & 7;
    float acc[8];
#pragma unroll
    for (int k = 0; k < 8; k++) acc[k] = 0.f;
    float dsum = 0.f;

#define AGG1_ROUND(E_) { \
        int se = __shfl(s, (E_)); \
        float we = __shfl(w, (E_)); \
        uint4 u = ((const uint4*)(h1b + (size_t)se * C1))[cq]; \
        float f0, f1; \
        bf16x2_unpack(u.x, f0, f1); acc[0]=fmaf(we,f0,acc[0]); acc[1]=fmaf(we,f1,acc[1]); \
        bf16x2_unpack(u.y, f0, f1); acc[2]=fmaf(we,f0,acc[2]); acc[3]=fmaf(we,f1,acc[3]); \
        bf16x2_unpack(u.z, f0, f1); acc[4]=fmaf(we,f0,acc[4]); acc[5]=fmaf(we,f1,acc[5]); \
        bf16x2_unpack(u.w, f0, f1); acc[6]=fmaf(we,f0,acc[6]); acc[7]=fmaf(we,f1,acc[7]); }

    for (int base = beg; base < end; base += 64) {
        int cnt = min(64, end - base);
        int s = d; float w = 0.f;
        if (lane < cnt) {
            s = adj[base + lane];
            float lg = as1[s] + adv;
            lg = lg > 0.f ? lg : NEG_SLOPE * lg;
            w = expf(lg);
            dsum += w;
        }
        int j = 0;
        for (; j + 32 <= cnt; j += 32) {
            AGG1_ROUND(j + g)
            AGG1_ROUND(j + 8 + g)
            AGG1_ROUND(j + 16 + g)
            AGG1_ROUND(j + 24 + g)
        }
        for (; j < cnt; j += 8) AGG1_ROUND(j + g)
    }
#undef AGG1_ROUND

#pragma unroll
    for (int off = 32; off > 0; off >>= 1) dsum += __shfl_xor(dsum, off);
#pragma unroll
    for (int off = 8; off <= 32; off <<= 1) {
#pragma unroll
        for (int k = 0; k < 8; k++) acc[k] += __shfl_xor(acc[k], off);
    }
    if (g == 0) {
        float inv = 1.f / dsum;
        float4 bv0 = ((const float4*)b1)[cq * 2];
        float4 bv1 = ((const float4*)b1)[cq * 2 + 1];
        float4 o0, o1;
        o0.x = acc[0] * inv + bv0.x; o0.x = o0.x > 0.f ? o0.x : 0.f;
        o0.y = acc[1] * inv + bv0.y; o0.y = o0.y > 0.f ? o0.y : 0.f;
        o0.z = acc[2] * inv + bv0.z; o0.z = o0.z > 0.f ? o0.z : 0.f;
        o0.w = acc[3] * inv + bv0.w; o0.w = o0.w > 0.f ? o0.w : 0.f;
        o1.x = acc[4] * inv + bv1.x; o1.x = o1.x > 0.f ? o1.x : 0.f;
        o1.y = acc[5] * inv + bv1.y; o1.y = o1.y > 0.f ? o1.y : 0.f;
        o1.z = acc[6] * inv + bv1.z; o1.z = o1.z > 0.f ? o1.z : 0.f;
        o1.w = acc[7] * inv + bv1.w; o1.w = o1.w > 0.f ? o1.w : 0.f;
        float4* op = (float4*)(h1out + (size_t)d * C1 + cq * 8);
        op[0] = o0; op[1] = o1;
    }
}

// ---------------- GEMM2 + alpha2: stores bf16 h2b; as2/ad2 from exact fp32 ----------------

__global__ __launch_bounds__(256)
void k_gemm2(const float* __restrict__ h1out, const float* __restrict__ W2,
             const float* __restrict__ attS, const float* __restrict__ attD,
             ushort16* __restrict__ h2b, float* __restrict__ as2,
             float* __restrict__ ad2, int n) {
    __shared__ float w2t[C2 * 68];
    __shared__ float sAttS[C2], sAttD[C2];
    int t = threadIdx.x;
    for (int i = t; i < C1 * C2; i += 256) {
        int k = i >> 5, c = i & 31;
        w2t[c * 68 + k] = W2[i];
    }
    if (t < C2) { sAttS[t] = attS[t]; sAttD[t] = attD[t]; }
    __syncthreads();
    int wave = t >> 6, lane = t & 63;
    int col = lane & 31, half = lane >> 5;
    int rowbase = blockIdx.x * 32 + wave * 8;
    const float* wrow = &w2t[col * 68];
    for (int rr = 0; rr < 8; rr += 2) {
        int row = rowbase + rr + half;
        if (row >= n) return;
        float acc = 0.f;
#pragma unroll
        for (int k = 0; k < C1; k += 4) {
            float4 wv = *(const float4*)&wrow[k];
            float4 xv = *(const float4*)&h1out[(size_t)row * C1 + k];
            acc = fmaf(xv.x, wv.x, acc);
            acc = fmaf(xv.y, wv.y, acc);
            acc = fmaf(xv.z, wv.z, acc);
            acc = fmaf(xv.w, wv.w, acc);
        }
        h2b[(size_t)row * C2 + col] = (ushort16)bf16_rne(acc);
        float vs = acc * sAttS[col], vd = acc * sAttD[col];
#pragma unroll
        for (int off = 16; off > 0; off >>= 1) {
            vs += __shfl_xor(vs, off);
            vd += __shfl_xor(vd, off);
        }
        if (col == 0) { as2[row] = vs; ad2[row] = vd; }
    }
}

// ---------------- Layer-2 aggregation (bf16 gather, 64B rows) -> emb ----------------

__global__ __launch_bounds__(256)
void k_agg2(const ushort16* __restrict__ h2b, const float* __restrict__ as2,
            const float* __restrict__ ad2, const int* __restrict__ row_ptr,
            const int* __restrict__ adj, const float* __restrict__ b2,
            float* __restrict__ emb, int n) {
    int wave = (blockIdx.x * 256 + threadIdx.x) >> 6;
    int lane = threadIdx.x & 63;
    if (wave >= n) return;
    int d = wave;
    int beg = row_ptr[d], end = row_ptr[d + 1];
    float adv = ad2[d];
    int g = lane >> 2, cq = lane & 3;
    float acc[8];
#pragma unroll
    for (int k = 0; k < 8; k++) acc[k] = 0.f;
    float dsum = 0.f;

#define AGG2_ROUND(E_) { \
        int se = __shfl(s, (E_)); \
        float we = __shfl(w, (E_)); \
        uint4 u = ((const uint4*)(h2b + (size_t)se * C2))[cq]; \
        float f0, f1; \
        bf16x2_unpack(u.x, f0, f1); acc[0]=fmaf(we,f0,acc[0]); acc[1]=fmaf(we,f1,acc[1]); \
        bf16x2_unpack(u.y, f0, f1); acc[2]=fmaf(we,f0,acc[2]); acc[3]=fmaf(we,f1,acc[3]); \
        bf16x2_unpack(u.z, f0, f1); acc[4]=fmaf(we,f0,acc[4]); acc[5]=fmaf(we,f1,acc[5]); \
        bf16x2_unpack(u.w, f0, f1); acc[6]=fmaf(we,f0,acc[6]); acc[7]=fmaf(we,f1,acc[7]); }

    for (int base = beg; base < end; base += 64) {
        int cnt = min(64, end - base);
        int s = d; float w = 0.f;
        if (lane < cnt) {
            s = adj[base + lane];
            float lg = as2[s] + adv;
            lg = lg > 0.f ? lg : NEG_SLOPE * lg;
            w = expf(lg);
            dsum += w;
        }
        int j = 0;
        for (; j + 64 <= cnt; j += 64) {
            AGG2_ROUND(j + g)
            AGG2_ROUND(j + 16 + g)
            AGG2_ROUND(j + 32 + g)
            AGG2_ROUND(j + 48 + g)
        }
        for (; j < cnt; j += 16) AGG2_ROUND(j + g)
    }
#undef AGG2_ROUND

#pragma unroll
    for (int off = 32; off > 0; off >>= 1) dsum += __shfl_xor(dsum, off);
#pragma unroll
    for (int off = 4; off <= 32; off <<= 1) {
#pragma unroll
        for (int k = 0; k < 8; k++) acc[k] += __shfl_xor(acc[k], off);
    }
    if (g == 0) {
        float inv = 1.f / dsum;
        float4 bv0 = ((const float4*)b2)[cq * 2];
        float4 bv1 = ((const float4*)b2)[cq * 2 + 1];
        float4 o0, o1;
        o0.x = acc[0] * inv + bv0.x; o0.x = o0.x > 0.f ? o0.x : 0.f;
        o0.y = acc[1] * inv + bv0.y; o0.y = o0.y > 0.f ? o0.y : 0.f;
        o0.z = acc[2] * inv + bv0.z; o0.z = o0.z > 0.f ? o0.z : 0.f;
        o0.w = acc[3] * inv + bv0.w; o0.w = o0.w > 0.f ? o0.w : 0.f;
        o1.x = acc[4] * inv + bv1.x; o1.x = o1.x > 0.f ? o1.x : 0.f;
        o1.y = acc[5] * inv + bv1.y; o1.y = o1.y > 0.f ? o1.y : 0.f;
        o1.z = acc[6] * inv + bv1.z; o1.z = o1.z > 0.f ? o1.z : 0.f;
        o1.w = acc[7] * inv + bv1.w; o1.w = o1.w > 0.f ? o1.w : 0.f;
        float4* op = (float4*)(emb + (size_t)d * C2 + cq * 8);
        op[0] = o0; op[1] = o1;
    }
}

// ---------------- logits = emb @ fcW + fcb ----------------

__global__ __launch_bounds__(256)
void k_logits(const float* __restrict__ emb, const float* __restrict__ fcW,
              const float* __restrict__ fcb, float* __restrict__ out, int n) {
    __shared__ float w[C2 * ODIM];
    __shared__ float b[ODIM];
    int t = threadIdx.x;
    for (int i = t; i < C2 * ODIM; i += 256) w[i] = fcW[i];
    if (t < ODIM) b[t] = fcb[t];
    __syncthreads();
    int lane = t & 63;
    int row = blockIdx.x * 4 + (t >> 6);
    if (row >= n) return;
    float acc = (lane < ODIM) ? b[lane] : 0.f;
    const float4* er = (const float4*)&emb[(size_t)row * C2];
#pragma unroll
    for (int c4 = 0; c4 < 8; c4++) {
        float4 e = er[c4];
        int c = c4 * 4;
        if (lane < ODIM) {
            acc = fmaf(e.x, w[(c + 0) * ODIM + lane], acc);
            acc = fmaf(e.y, w[(c + 1) * ODIM + lane], acc);
            acc = fmaf(e.z, w[(c + 2) * ODIM + lane], acc);
            acc = fmaf(e.w, w[(c + 3) * ODIM + lane], acc);
        }
    }
    if (lane < ODIM) out[(size_t)row * ODIM + lane] = acc;
}

// ---------------- launch ----------------

extern "C" void kernel_launch(void* const* d_in, const int* in_sizes, int n_in,
                              void* d_out, int out_size, void* d_ws, size_t ws_size,
                              hipStream_t stream) {
    const float* x    = (const float*)d_in[0];
    const int*   ei   = (const int*)d_in[1];
    const float* W1   = (const float*)d_in[2];
    const float* aS1  = (const float*)d_in[3];
    const float* aD1  = (const float*)d_in[4];
    const float* b1   = (const float*)d_in[5];
    const float* W2   = (const float*)d_in[6];
    const float* aS2  = (const float*)d_in[7];
    const float* aD2  = (const float*)d_in[8];
    const float* b2   = (const float*)d_in[9];
    const float* fcW  = (const float*)d_in[10];
    const float* fcb  = (const float*)d_in[11];

    const int N = in_sizes[0] / IN_DIM;
    const int E = in_sizes[1] / 2;
    const int* src = ei;
    const int* dst = ei + E;

    // workspace layout
    ushort16* h1b = (ushort16*)d_ws;                 // N*64 ushorts (12.8MB); pre-gemm1: chist
    float* h1out  = (float*)((char*)d_ws + (size_t)N * C1 * 2);  // N*64 floats (pre-agg1: pairs)
    float* as1    = h1out + (size_t)N * C1;          // N
    float* ad1    = as1 + N;
    float* as2    = ad1 + N;
    float* ad2    = as2 + N;
    float* asP    = ad2 + N;                         // 2N
    float* adP    = asP + 2 * (size_t)N;             // 2N
    int*   cnt    = (int*)(adP + 2 * (size_t)N);     // N
    int*   row_ptr = cnt + N;                        // N+1
    int*   bsums   = row_ptr + (N + 1);              // <=256
    int*   adj     = bsums + 256;                    // E+N
    int*   gh      = adj + (E + N);                  // nb*nblkE (~10K)

    unsigned* pairs = (unsigned*)h1out;              // E packed uints; dead after k_place2
    int*  chist = (int*)h1b;                         // nb*CH*4096 ints; dead before gemm1
    ushort16* h2b = (ushort16*)h1b;                  // N*32 ushorts; h1b dead after agg1

    float* emb    = (float*)d_out;                   // N*32
    float* logits = emb + (size_t)N * C2;            // N*40

    int nbN   = (N + 255) / 256;
    int nbS   = (N + SCAN_CHUNK - 1) / SCAN_CHUNK;   // 25
    int nblkE = (E + ECHUNK - 1) / ECHUNK;           // ~391
    int nb    = (N + (1 << BSHIFT) - 1) >> BSHIFT;   // ~25 buckets (<= 32)
    int nBC   = 8 * 4 * CH;

    // CSR build — no per-edge global atomics; packed pairs + contiguous bplace writes
    k_bhist<<<nblkE, 256, 0, stream>>>(dst, E, gh, nblkE, nb);
    k_bscan<<<1, 256, 0, stream>>>(gh, nb * nblkE);
    k_bplace<<<nblkE, 256, 0, stream>>>(src, dst, E, gh, nblkE, nb, pairs);
    k_nhist<<<nBC, 512, 0, stream>>>(pairs, gh, nblkE, nb, E, chist);
    k_cnt<<<nbN, 256, 0, stream>>>(chist, cnt, N);
    k_scan1<<<nbS, 256, 0, stream>>>(cnt, N, bsums);
    k_scan2<<<1, 256, 0, stream>>>(bsums, nbS, row_ptr, N, E + N);
    k_scan3<<<nbS, 256, 0, stream>>>(cnt, N, bsums, row_ptr);
    k_selfloop<<<nbN, 256, 0, stream>>>(row_ptr, N, adj);
    k_nscan<<<nbN, 256, 0, stream>>>(chist, row_ptr, N);
    k_place2<<<nBC, 512, 0, stream>>>(pairs, gh, nblkE, nb, E, chist, adj, 0);

    // GAT layers
    int nbG1 = 2 * ((N + 255) / 256);   // x2: column halves
    k_gemm1<<<nbG1, 256, 0, stream>>>(x, W1, aS1, aD1, h1b, asP, adP, N);
    k_alphaC<<<nbN, 256, 0, stream>>>(asP, adP, as1, ad1, N);
    int nbA = (N + 3) / 4;
    k_agg1<<<nbA, 256, 0, stream>>>(h1b, as1, ad1, row_ptr, adj, b1, h1out, N);
    int nbG2 = (N + 31) / 32;
    k_gemm2<<<nbG2, 256, 0, stream>>>(h1out, W2, aS2, aD2, h2b, as2, ad2, N);
    k_agg2<<<nbA, 256, 0, stream>>>(h2b, as2, ad2, row_ptr, adj, b2, emb, N);
    k_logits<<<nbA, 256, 0, stream>>>(emb, fcW, fcb, logits, N);
}

// Round 18
// 387.703 us; speedup vs baseline: 1.3775x; 1.0879x over previous
//
#include <hip/hip_runtime.h>
#include <hip/hip_bf16.h>

#define NEG_SLOPE 0.2f
#define IN_DIM 256
#define C1 64
#define C2 32
#define ODIM 40
#define SCAN_CHUNK 4096   // 256 threads * 16 items
#define BSHIFT 12         // bucket = dst >> 12 (4096 nodes/bucket)
#define ECHUNK 8192       // edges per block in bucket passes
#define ECH2 8192         // edges per (bucket,chunk) block in node passes
#define CH 20             // max chunks per bucket (CH*ECH2=164K >> 131K+5sigma)
#define SRCMASK 0x1FFFF   // 17 bits: src < 131072

typedef unsigned short ushort16;

__device__ __forceinline__ unsigned bf16_rne(float f) {
    unsigned a = __float_as_uint(f);
    return (a + 0x7FFFu + ((a >> 16) & 1u)) >> 16;   // low 16 bits valid
}
__device__ __forceinline__ void bf16x2_unpack(unsigned u, float& f0, float& f1) {
    f0 = __uint_as_float(u << 16);
    f1 = __uint_as_float(u & 0xFFFF0000u);
}

// ---------------- CSR build: bucket sort (packed uints), then in-bucket counting sort ----

__global__ void k_bhist(const int* __restrict__ dst, int E, int* __restrict__ gh,
                        int nblk, int nb) {
    __shared__ int h[32];
    int t = threadIdx.x;
    if (t < 32) h[t] = 0;
    __syncthreads();
    int base = blockIdx.x * ECHUNK;
    int end = min(base + ECHUNK, E);
    for (int i = base + t; i < end; i += 256) atomicAdd(&h[dst[i] >> BSHIFT], 1);
    __syncthreads();
    if (t < nb) gh[t * nblk + blockIdx.x] = h[t];
}

// parallel exclusive scan of gh[0..L): 3-phase (block sums, scan sums, add back)
__global__ void k_gs1(const int* __restrict__ gh, int L, int* __restrict__ gsums) {
    __shared__ int lds[256];
    int t = threadIdx.x;
    int base = blockIdx.x * SCAN_CHUNK + t * 16;
    int s = 0;
#pragma unroll
    for (int i = 0; i < 16; i++) { int idx = base + i; s += (idx < L) ? gh[idx] : 0; }
    lds[t] = s; __syncthreads();
    for (int off = 128; off > 0; off >>= 1) {
        if (t < off) lds[t] += lds[t + off];
        __syncthreads();
    }
    if (t == 0) gsums[blockIdx.x] = lds[0];
}

__global__ void k_gs2(int* __restrict__ gsums, int nblks) {
    __shared__ int lds[256];
    int t = threadIdx.x;
    int v = (t < nblks) ? gsums[t] : 0;
    lds[t] = v; __syncthreads();
    for (int off = 1; off < 256; off <<= 1) {
        int u = (t >= off) ? lds[t - off] : 0;
        __syncthreads();
        lds[t] += u;
        __syncthreads();
    }
    if (t < nblks) gsums[t] = lds[t] - v;  // exclusive
}

__global__ void k_gs3(int* __restrict__ gh, int L, const int* __restrict__ gsums) {
    __shared__ int lds[256];
    int t = threadIdx.x;
    int base = blockIdx.x * SCAN_CHUNK + t * 16;
    int loc[16];
    int s = 0;
#pragma unroll
    for (int i = 0; i < 16; i++) {
        int idx = base + i;
        int c = (idx < L) ? gh[idx] : 0;
        loc[i] = s; s += c;
    }
    lds[t] = s; __syncthreads();
    for (int off = 1; off < 256; off <<= 1) {
        int u = (t >= off) ? lds[t - off] : 0;
        __syncthreads();
        lds[t] += u;
        __syncthreads();
    }
    int texcl = lds[t] - s + gsums[blockIdx.x];
#pragma unroll
    for (int i = 0; i < 16; i++) {
        int idx = base + i;
        if (idx < L) gh[idx] = texcl + loc[i];
    }
}

// bucket-partition edges into packed uints; block-local LDS sort so global
// writes are contiguous coalesced runs (no random 8B scatter).
__global__ __launch_bounds__(256)
void k_bplace(const int* __restrict__ src, const int* __restrict__ dst, int E,
              const int* __restrict__ gh, int nblk, int nb,
              unsigned* __restrict__ pairs) {
    __shared__ int cnt32[32], lofs[33], lcur[32], delta[32];
    __shared__ unsigned buf[ECHUNK];   // 32 KB
    int t = threadIdx.x;
    if (t < 32) cnt32[t] = 0;
    __syncthreads();
    int base = blockIdx.x * ECHUNK;
    int end = min(base + ECHUNK, E);
    for (int i = base + t; i < end; i += 256) atomicAdd(&cnt32[dst[i] >> BSHIFT], 1);
    __syncthreads();
    if (t == 0) {
        int s = 0;
        for (int b = 0; b < 32; b++) { lofs[b] = s; s += cnt32[b]; }
        lofs[32] = s;
    }
    __syncthreads();
    if (t < 32) {
        lcur[t] = lofs[t];
        delta[t] = (t < nb) ? (gh[t * nblk + blockIdx.x] - lofs[t]) : 0;
    }
    __syncthreads();
    for (int i = base + t; i < end; i += 256) {
        int d = dst[i];
        int b = d >> BSHIFT;
        int p = atomicAdd(&lcur[b], 1);
        buf[p] = (unsigned)src[i] | ((unsigned)(d & 4095) << 17);
    }
    __syncthreads();
    int m = end - base;
    for (int j = t; j < m; j += 256) {
        int lo = 0, hi = 31;
        while (lo < hi) { int mid = (lo + hi + 1) >> 1; if (lofs[mid] <= j) lo = mid; else hi = mid - 1; }
        pairs[j + delta[lo]] = buf[j];
    }
}

__device__ __forceinline__ void bc_map(int blk, int* b, int* c) {
    int xcd = blk & 7, k = blk >> 3;
    *b = (k & 3) * 8 + xcd;
    *c = k >> 2;
}

__global__ __launch_bounds__(512)
void k_nhist(const unsigned* __restrict__ pairs, const int* __restrict__ gh, int nblk,
             int nb, int E, int* __restrict__ chist) {
    __shared__ int h[4096];
    int b, c; bc_map(blockIdx.x, &b, &c);
    if (b >= nb) return;
    for (int i = threadIdx.x; i < 4096; i += 512) h[i] = 0;
    __syncthreads();
    int estart = gh[b * nblk];
    int eend = (b + 1 < nb) ? gh[(b + 1) * nblk] : E;
    int s0 = estart + c * ECH2;
    int s1 = min(s0 + ECH2, eend);
    for (int i = s0 + threadIdx.x; i < s1; i += 512)
        atomicAdd(&h[(pairs[i] >> 17) & 4095], 1);
    __syncthreads();
    int* out = chist + ((size_t)b * CH + c) * 4096;
    for (int i = threadIdx.x; i < 4096; i += 512) out[i] = h[i];
}

__global__ void k_cnt(const int* __restrict__ chist, int* __restrict__ cnt, int n) {
    int i = blockIdx.x * 256 + threadIdx.x;
    if (i >= n) return;
    int b = i >> BSHIFT, j = i & 4095;
    const int* p = chist + ((size_t)b * CH) * 4096 + j;
    int s = 1;
#pragma unroll
    for (int c = 0; c < CH; c++) s += p[c * 4096];
    cnt[i] = s;
}

__global__ void k_scan1(const int* __restrict__ cnt, int n, int* __restrict__ bsums) {
    __shared__ int lds[256];
    int t = threadIdx.x;
    int base = blockIdx.x * SCAN_CHUNK + t * 16;
    int s = 0;
#pragma unroll
    for (int i = 0; i < 16; i++) { int idx = base + i; s += (idx < n) ? cnt[idx] : 0; }
    lds[t] = s; __syncthreads();
    for (int off = 128; off > 0; off >>= 1) {
        if (t < off) lds[t] += lds[t + off];
        __syncthreads();
    }
    if (t == 0) bsums[blockIdx.x] = lds[0];
}

__global__ void k_scan2(int* bsums, int nb, int* row_ptr, int n, int total) {
    __shared__ int lds[256];
    int t = threadIdx.x;
    int v = (t < nb) ? bsums[t] : 0;
    lds[t] = v; __syncthreads();
    for (int off = 1; off < 256; off <<= 1) {
        int u = (t >= off) ? lds[t - off] : 0;
        __syncthreads();
        lds[t] += u;
        __syncthreads();
    }
    if (t < nb) bsums[t] = lds[t] - v;
    if (t == 0) row_ptr[n] = total;
}

__global__ void k_scan3(const int* __restrict__ cnt, int n, const int* __restrict__ bsums,
                        int* __restrict__ row_ptr) {
    __shared__ int lds[256];
    int t = threadIdx.x;
    int base = blockIdx.x * SCAN_CHUNK + t * 16;
    int loc[16];
    int s = 0;
#pragma unroll
    for (int i = 0; i < 16; i++) {
        int idx = base + i;
        int c = (idx < n) ? cnt[idx] : 0;
        loc[i] = s; s += c;
    }
    lds[t] = s; __syncthreads();
    for (int off = 1; off < 256; off <<= 1) {
        int u = (t >= off) ? lds[t - off] : 0;
        __syncthreads();
        lds[t] += u;
        __syncthreads();
    }
    int texcl = lds[t] - s + bsums[blockIdx.x];
#pragma unroll
    for (int i = 0; i < 16; i++) {
        int idx = base + i;
        if (idx < n) row_ptr[idx] = texcl + loc[i];
    }
}

// nscan: convert chist to absolute cursors AND write self-loop (merged k_selfloop)
__global__ void k_nscan(int* __restrict__ chist, const int* __restrict__ row_ptr,
                        int* __restrict__ adj, int n) {
    int i = blockIdx.x * 256 + threadIdx.x;
    if (i >= n) return;
    int rp = row_ptr[i];
    adj[rp] = i;                       // self-loop at slot 0
    int b = i >> BSHIFT, j = i & 4095;
    int* p = chist + ((size_t)b * CH) * 4096 + j;
    int s = rp + 1;
#pragma unroll
    for (int c = 0; c < CH; c++) { int t = p[c * 4096]; p[c * 4096] = s; s += t; }
}

__global__ __launch_bounds__(512)
void k_place2(const unsigned* __restrict__ pairs, const int* __restrict__ gh, int nblk,
              int nb, int E, const int* __restrict__ chist, int* __restrict__ adj) {
    __shared__ int cur[4096];
    int b, c; bc_map(blockIdx.x, &b, &c);
    if (b >= nb) return;
    const int* cs = chist + ((size_t)b * CH + c) * 4096;
    for (int i = threadIdx.x; i < 4096; i += 512) cur[i] = cs[i];
    __syncthreads();
    int estart = gh[b * nblk];
    int eend = (b + 1 < nb) ? gh[(b + 1) * nblk] : E;
    int s0 = estart + c * ECH2;
    int s1 = min(s0 + ECH2, eend);
    for (int i = s0 + threadIdx.x; i < s1; i += 512) {
        unsigned p = pairs[i];
        int pos = atomicAdd(&cur[(p >> 17) & 4095], 1);
        adj[pos] = (int)(p & SRCMASK);
    }
}

// ---------------- GEMM1: h1b(bf16) = x @ W1; partial alpha from exact fp32 acc ----------------
// [r12/r15/r17-measured: 123us, VGPR 32, no spill — frozen]

__global__ __launch_bounds__(256, 4)
void k_gemm1(const float* __restrict__ x, const float* __restrict__ W1,
             const float* __restrict__ attS, const float* __restrict__ attD,
             ushort16* __restrict__ h1b, float* __restrict__ asP,
             float* __restrict__ adP, int n) {
    int t = threadIdx.x;
    int wave = t >> 6, lane = t & 63;
    int half = blockIdx.x & 1;
    int chalf = half * 32;                              // block-uniform column half
    int row = (blockIdx.x >> 1) * 256 + wave * 64 + lane;
    bool active = row < n;
    int rowc = active ? row : n - 1;
    const float4* xr = (const float4*)(x + (size_t)rowc * IN_DIM);

    float acc[32];
#pragma unroll
    for (int c = 0; c < 32; c++) acc[c] = 0.f;

#define FMA_K(XC, KK) { \
        const float* wk = wb + (KK) * C1; \
        _Pragma("unroll") \
        for (int c = 0; c < 32; c++) acc[c] = fmaf((XC), wk[c], acc[c]); }

    for (int k0 = 0; k0 < 16; k0++) {                   // BK = 16
        float4 xv0 = xr[k0 * 4 + 0];
        float4 xv1 = xr[k0 * 4 + 1];
        float4 xv2 = xr[k0 * 4 + 2];
        float4 xv3 = xr[k0 * 4 + 3];
        const float* wb = W1 + (size_t)(k0 * 16) * C1 + chalf;  // uniform
        FMA_K(xv0.x, 0)  FMA_K(xv0.y, 1)  FMA_K(xv0.z, 2)  FMA_K(xv0.w, 3)
        FMA_K(xv1.x, 4)  FMA_K(xv1.y, 5)  FMA_K(xv1.z, 6)  FMA_K(xv1.w, 7)
        FMA_K(xv2.x, 8)  FMA_K(xv2.y, 9)  FMA_K(xv2.z, 10) FMA_K(xv2.w, 11)
        FMA_K(xv3.x, 12) FMA_K(xv3.y, 13) FMA_K(xv3.z, 14) FMA_K(xv3.w, 15)
    }
#undef FMA_K

    if (!active) return;
    float vs = 0.f, vd = 0.f;
#pragma unroll
    for (int c = 0; c < 32; c++) {
        vs = fmaf(acc[c], attS[chalf + c], vs);   // uniform -> SGPR
        vd = fmaf(acc[c], attD[chalf + c], vd);
    }
    asP[half * n + row] = vs;
    adP[half * n + row] = vd;

    uint4* hp = (uint4*)((ushort16*)h1b + (size_t)row * C1 + chalf);
#pragma unroll
    for (int j = 0; j < 4; j++) {
        unsigned p0 = bf16_rne(acc[j*8+0]) | (bf16_rne(acc[j*8+1]) << 16);
        unsigned p1 = bf16_rne(acc[j*8+2]) | (bf16_rne(acc[j*8+3]) << 16);
        unsigned p2 = bf16_rne(acc[j*8+4]) | (bf16_rne(acc[j*8+5]) << 16);
        unsigned p3 = bf16_rne(acc[j*8+6]) | (bf16_rne(acc[j*8+7]) << 16);
        hp[j] = make_uint4(p0, p1, p2, p3);
    }
}

// combine per-half alpha partials
__global__ void k_alphaC(const float* __restrict__ asP, const float* __restrict__ adP,
                         float* __restrict__ as1, float* __restrict__ ad1, int n) {
    int i = blockIdx.x * 256 + threadIdx.x;
    if (i < n) {
        as1[i] = asP[i] + asP[(size_t)n + i];
        ad1[i] = adP[i] + adP[(size_t)n + i];
    }
}

// ---------------- Layer-1 aggregation (bf16 gather, 128B rows) ----------------

__global__ __launch_bounds__(256)
void k_agg1(const ushort16* __restrict__ h1b, const float* __restrict__ as1,
            const float* __restrict__ ad1, const int* __restrict__ row_ptr,
            const int* __restrict__ adj, const float* __restrict__ b1,
            float* __restrict__ h1out, int n) {
    int wave = (blockIdx.x * 256 + threadIdx.x) >> 6;
    int lane = threadIdx.x & 63;
    if (wave >= n) return;
    int d = wave;
    int beg = row_ptr[d], end = row_ptr[d + 1];
    float adv = ad1[d];
    int g = lane >> 3, cq = lane & 7;
    float acc[8];
#pragma unroll
    for (int k = 0; k < 8; k++) acc[k] = 0.f;
    float dsum = 0.f;

#define AGG1_ROUND(E_) { \
        int se = __shfl(s, (E_)); \
        float we = __shfl(w, (E_)); \
        uint4 u = ((const uint4*)(h1b + (size_t)se * C1))[cq]; \
        float f0, f1; \
        bf16x2_unpack(u.x, f0, f1); acc[0]=fmaf(we,f0,acc[0]); acc[1]=fmaf(we,f1,acc[1]); \
        bf16x2_unpack(u.y, f0, f1); acc[2]=fmaf(we,f0,acc[2]); acc[3]=fmaf(we,f1,acc[3]); \
        bf16x2_unpack(u.z, f0, f1); acc[4]=fmaf(we,f0,acc[4]); acc[5]=fmaf(we,f1,acc[5]); \
        bf16x2_unpack(u.w, f0, f1); acc[6]=fmaf(we,f0,acc[6]); acc[7]=fmaf(we,f1,acc[7]); }

    for (int base = beg; base < end; base += 64) {
        int cnt = min(64, end - base);
        int s = d; float w = 0.f;
        if (lane < cnt) {
            s = adj[base + lane];
            float lg = as1[s] + adv;
            lg = lg > 0.f ? lg : NEG_SLOPE * lg;
            w = expf(lg);
            dsum += w;
        }
        int j = 0;
        for (; j + 32 <= cnt; j += 32) {
            AGG1_ROUND(j + g)
            AGG1_ROUND(j + 8 + g)
            AGG1_ROUND(j + 16 + g)
            AGG1_ROUND(j + 24 + g)
        }
        for (; j < cnt; j += 8) AGG1_ROUND(j + g)
    }
#undef AGG1_ROUND

#pragma unroll
    for (int off = 32; off > 0; off >>= 1) dsum += __shfl_xor(dsum, off);
#pragma unroll
    for (int off = 8; off <= 32; off <<= 1) {
#pragma unroll
        for (int k = 0; k < 8; k++) acc[k] += __shfl_xor(acc[k], off);
    }
    if (g == 0) {
        float inv = 1.f / dsum;
        float4 bv0 = ((const float4*)b1)[cq * 2];
        float4 bv1 = ((const float4*)b1)[cq * 2 + 1];
        float4 o0, o1;
        o0.x = acc[0] * inv + bv0.x; o0.x = o0.x > 0.f ? o0.x : 0.f;
        o0.y = acc[1] * inv + bv0.y; o0.y = o0.y > 0.f ? o0.y : 0.f;
        o0.z = acc[2] * inv + bv0.z; o0.z = o0.z > 0.f ? o0.z : 0.f;
        o0.w = acc[3] * inv + bv0.w; o0.w = o0.w > 0.f ? o0.w : 0.f;
        o1.x = acc[4] * inv + bv1.x; o1.x = o1.x > 0.f ? o1.x : 0.f;
        o1.y = acc[5] * inv + bv1.y; o1.y = o1.y > 0.f ? o1.y : 0.f;
        o1.z = acc[6] * inv + bv1.z; o1.z = o1.z > 0.f ? o1.z : 0.f;
        o1.w = acc[7] * inv + bv1.w; o1.w = o1.w > 0.f ? o1.w : 0.f;
        float4* op = (float4*)(h1out + (size_t)d * C1 + cq * 8);
        op[0] = o0; op[1] = o1;
    }
}

// ---------------- GEMM2 + alpha2: stores bf16 h2b; as2/ad2 from exact fp32 ----------------

__global__ __launch_bounds__(256)
void k_gemm2(const float* __restrict__ h1out, const float* __restrict__ W2,
             const float* __restrict__ attS, const float* __restrict__ attD,
             ushort16* __restrict__ h2b, float* __restrict__ as2,
             float* __restrict__ ad2, int n) {
    __shared__ float w2t[C2 * 68];
    __shared__ float sAttS[C2], sAttD[C2];
    int t = threadIdx.x;
    for (int i = t; i < C1 * C2; i += 256) {
        int k = i >> 5, c = i & 31;
        w2t[c * 68 + k] = W2[i];
    }
    if (t < C2) { sAttS[t] = attS[t]; sAttD[t] = attD[t]; }
    __syncthreads();
    int wave = t >> 6, lane = t & 63;
    int col = lane & 31, half = lane >> 5;
    int rowbase = blockIdx.x * 32 + wave * 8;
    const float* wrow = &w2t[col * 68];
    for (int rr = 0; rr < 8; rr += 2) {
        int row = rowbase + rr + half;
        if (row >= n) return;
        float acc = 0.f;
#pragma unroll
        for (int k = 0; k < C1; k += 4) {
            float4 wv = *(const float4*)&wrow[k];
            float4 xv = *(const float4*)&h1out[(size_t)row * C1 + k];
            acc = fmaf(xv.x, wv.x, acc);
            acc = fmaf(xv.y, wv.y, acc);
            acc = fmaf(xv.z, wv.z, acc);
            acc = fmaf(xv.w, wv.w, acc);
        }
        h2b[(size_t)row * C2 + col] = (ushort16)bf16_rne(acc);
        float vs = acc * sAttS[col], vd = acc * sAttD[col];
#pragma unroll
        for (int off = 16; off > 0; off >>= 1) {
            vs += __shfl_xor(vs, off);
            vd += __shfl_xor(vd, off);
        }
        if (col == 0) { as2[row] = vs; ad2[row] = vd; }
    }
}

// ---------------- Layer-2 aggregation (bf16 gather, 64B rows) -> emb ----------------

__global__ __launch_bounds__(256)
void k_agg2(const ushort16* __restrict__ h2b, const float* __restrict__ as2,
            const float* __restrict__ ad2, const int* __restrict__ row_ptr,
            const int* __restrict__ adj, const float* __restrict__ b2,
            float* __restrict__ emb, int n) {
    int wave = (blockIdx.x * 256 + threadIdx.x) >> 6;
    int lane = threadIdx.x & 63;
    if (wave >= n) return;
    int d = wave;
    int beg = row_ptr[d], end = row_ptr[d + 1];
    float adv = ad2[d];
    int g = lane >> 2, cq = lane & 3;
    float acc[8];
#pragma unroll
    for (int k = 0; k < 8; k++) acc[k] = 0.f;
    float dsum = 0.f;

#define AGG2_ROUND(E_) { \
        int se = __shfl(s, (E_)); \
        float we = __shfl(w, (E_)); \
        uint4 u = ((const uint4*)(h2b + (size_t)se * C2))[cq]; \
        float f0, f1; \
        bf16x2_unpack(u.x, f0, f1); acc[0]=fmaf(we,f0,acc[0]); acc[1]=fmaf(we,f1,acc[1]); \
        bf16x2_unpack(u.y, f0, f1); acc[2]=fmaf(we,f0,acc[2]); acc[3]=fmaf(we,f1,acc[3]); \
        bf16x2_unpack(u.z, f0, f1); acc[4]=fmaf(we,f0,acc[4]); acc[5]=fmaf(we,f1,acc[5]); \
        bf16x2_unpack(u.w, f0, f1); acc[6]=fmaf(we,f0,acc[6]); acc[7]=fmaf(we,f1,acc[7]); }

    for (int base = beg; base < end; base += 64) {
        int cnt = min(64, end - base);
        int s = d; float w = 0.f;
        if (lane < cnt) {
            s = adj[base + lane];
            float lg = as2[s] + adv;
            lg = lg > 0.f ? lg : NEG_SLOPE * lg;
            w = expf(lg);
            dsum += w;
        }
        int j = 0;
        for (; j + 64 <= cnt; j += 64) {
            AGG2_ROUND(j + g)
            AGG2_ROUND(j + 16 + g)
            AGG2_ROUND(j + 32 + g)
            AGG2_ROUND(j + 48 + g)
        }
        for (; j < cnt; j += 16) AGG2_ROUND(j + g)
    }
#undef AGG2_ROUND

#pragma unroll
    for (int off = 32; off > 0; off >>= 1) dsum += __shfl_xor(dsum, off);
#pragma unroll
    for (int off = 4; off <= 32; off <<= 1) {
#pragma unroll
        for (int k = 0; k < 8; k++) acc[k] += __shfl_xor(acc[k], off);
    }
    if (g == 0) {
        float inv = 1.f / dsum;
        float4 bv0 = ((const float4*)b2)[cq * 2];
        float4 bv1 = ((const float4*)b2)[cq * 2 + 1];
        float4 o0, o1;
        o0.x = acc[0] * inv + bv0.x; o0.x = o0.x > 0.f ? o0.x : 0.f;
        o0.y = acc[1] * inv + bv0.y; o0.y = o0.y > 0.f ? o0.y : 0.f;
        o0.z = acc[2] * inv + bv0.z; o0.z = o0.z > 0.f ? o0.z : 0.f;
        o0.w = acc[3] * inv + bv0.w; o0.w = o0.w > 0.f ? o0.w : 0.f;
        o1.x = acc[4] * inv + bv1.x; o1.x = o1.x > 0.f ? o1.x : 0.f;
        o1.y = acc[5] * inv + bv1.y; o1.y = o1.y > 0.f ? o1.y : 0.f;
        o1.z = acc[6] * inv + bv1.z; o1.z = o1.z > 0.f ? o1.z : 0.f;
        o1.w = acc[7] * inv + bv1.w; o1.w = o1.w > 0.f ? o1.w : 0.f;
        float4* op = (float4*)(emb + (size_t)d * C2 + cq * 8);
        op[0] = o0; op[1] = o1;
    }
}

// ---------------- logits = emb @ fcW + fcb ----------------

__global__ __launch_bounds__(256)
void k_logits(const float* __restrict__ emb, const float* __restrict__ fcW,
              const float* __restrict__ fcb, float* __restrict__ out, int n) {
    __shared__ float w[C2 * ODIM];
    __shared__ float b[ODIM];
    int t = threadIdx.x;
    for (int i = t; i < C2 * ODIM; i += 256) w[i] = fcW[i];
    if (t < ODIM) b[t] = fcb[t];
    __syncthreads();
    int lane = t & 63;
    int row = blockIdx.x * 4 + (t >> 6);
    if (row >= n) return;
    float acc = (lane < ODIM) ? b[lane] : 0.f;
    const float4* er = (const float4*)&emb[(size_t)row * C2];
#pragma unroll
    for (int c4 = 0; c4 < 8; c4++) {
        float4 e = er[c4];
        int c = c4 * 4;
        if (lane < ODIM) {
            acc = fmaf(e.x, w[(c + 0) * ODIM + lane], acc);
            acc = fmaf(e.y, w[(c + 1) * ODIM + lane], acc);
            acc = fmaf(e.z, w[(c + 2) * ODIM + lane], acc);
            acc = fmaf(e.w, w[(c + 3) * ODIM + lane], acc);
        }
    }
    if (lane < ODIM) out[(size_t)row * ODIM + lane] = acc;
}

// ---------------- launch ----------------

extern "C" void kernel_launch(void* const* d_in, const int* in_sizes, int n_in,
                              void* d_out, int out_size, void* d_ws, size_t ws_size,
                              hipStream_t stream) {
    const float* x    = (const float*)d_in[0];
    const int*   ei   = (const int*)d_in[1];
    const float* W1   = (const float*)d_in[2];
    const float* aS1  = (const float*)d_in[3];
    const float* aD1  = (const float*)d_in[4];
    const float* b1   = (const float*)d_in[5];
    const float* W2   = (const float*)d_in[6];
    const float* aS2  = (const float*)d_in[7];
    const float* aD2  = (const float*)d_in[8];
    const float* b2   = (const float*)d_in[9];
    const float* fcW  = (const float*)d_in[10];
    const float* fcb  = (const float*)d_in[11];

    const int N = in_sizes[0] / IN_DIM;
    const int E = in_sizes[1] / 2;
    const int* src = ei;
    const int* dst = ei + E;

    // workspace layout
    ushort16* h1b = (ushort16*)d_ws;                 // N*64 ushorts (12.8MB); pre-gemm1: chist
    float* h1out  = (float*)((char*)d_ws + (size_t)N * C1 * 2);  // N*64 floats (pre-agg1: pairs)
    float* as1    = h1out + (size_t)N * C1;          // N
    float* ad1    = as1 + N;
    float* as2    = ad1 + N;
    float* ad2    = as2 + N;
    float* asP    = ad2 + N;                         // 2N
    float* adP    = asP + 2 * (size_t)N;             // 2N
    int*   cnt    = (int*)(adP + 2 * (size_t)N);     // N
    int*   row_ptr = cnt + N;                        // N+1
    int*   bsums   = row_ptr + (N + 1);              // <=256
    int*   gsums   = bsums + 256;                    // <=256
    int*   adj     = gsums + 256;                    // E+N
    int*   gh      = adj + (E + N);                  // nb*nblkE (~10K)

    unsigned* pairs = (unsigned*)h1out;              // E packed uints; dead after k_place2
    int*  chist = (int*)h1b;                         // nb*CH*4096 ints (8.2MB); dead pre-gemm1
    ushort16* h2b = (ushort16*)h1b;                  // N*32 ushorts; h1b dead after agg1

    float* emb    = (float*)d_out;                   // N*32
    float* logits = emb + (size_t)N * C2;            // N*40

    int nbN   = (N + 255) / 256;
    int nbS   = (N + SCAN_CHUNK - 1) / SCAN_CHUNK;   // 25
    int nblkE = (E + ECHUNK - 1) / ECHUNK;           // ~391
    int nb    = (N + (1 << BSHIFT) - 1) >> BSHIFT;   // ~25 buckets (<= 32)
    int nBC   = 32 * CH;                             // 640 (bucket, chunk) blocks
    int L     = nb * nblkE;                          // gh length
    int nbG   = (L + SCAN_CHUNK - 1) / SCAN_CHUNK;   // ~3

    // CSR build — no per-edge global atomics; parallel gh scan; merged selfloop
    k_bhist<<<nblkE, 256, 0, stream>>>(dst, E, gh, nblkE, nb);
    k_gs1<<<nbG, 256, 0, stream>>>(gh, L, gsums);
    k_gs2<<<1, 256, 0, stream>>>(gsums, nbG);
    k_gs3<<<nbG, 256, 0, stream>>>(gh, L, gsums);
    k_bplace<<<nblkE, 256, 0, stream>>>(src, dst, E, gh, nblkE, nb, pairs);
    k_nhist<<<nBC, 512, 0, stream>>>(pairs, gh, nblkE, nb, E, chist);
    k_cnt<<<nbN, 256, 0, stream>>>(chist, cnt, N);
    k_scan1<<<nbS, 256, 0, stream>>>(cnt, N, bsums);
    k_scan2<<<1, 256, 0, stream>>>(bsums, nbS, row_ptr, N, E + N);
    k_scan3<<<nbS, 256, 0, stream>>>(cnt, N, bsums, row_ptr);
    k_nscan<<<nbN, 256, 0, stream>>>(chist, row_ptr, adj, N);
    k_place2<<<nBC, 512, 0, stream>>>(pairs, gh, nblkE, nb, E, chist, adj);

    // GAT layers
    int nbG1 = 2 * ((N + 255) / 256);   // x2: column halves
    k_gemm1<<<nbG1, 256, 0, stream>>>(x, W1, aS1, aD1, h1b, asP, adP, N);
    k_alphaC<<<nbN, 256, 0, stream>>>(asP, adP, as1, ad1, N);
    int nbA = (N + 3) / 4;
    k_agg1<<<nbA, 256, 0, stream>>>(h1b, as1, ad1, row_ptr, adj, b1, h1out, N);
    int nbG2 = (N + 31) / 32;
    k_gemm2<<<nbG2, 256, 0, stream>>>(h1out, W2, aS2, aD2, h2b, as2, ad2, N);
    k_agg2<<<nbA, 256, 0, stream>>>(h2b, as2, ad2, row_ptr, adj, b2, emb, N);
    k_logits<<<nbA, 256, 0, stream>>>(emb, fcW, fcb, logits, N);
}